// Round 7
// baseline (144.876 us; speedup 1.0000x reference)
//
#include <hip/hip_runtime.h>
#include <math.h>

#define G 8             // samples per block -> grid 2048 = TWO residency generations
                        // (1024 resident): gen-2 phase-0 loads overlap gen-1 compute/stores
#define SR 16           // MFMA/latb/hbuf row count (verbatim r5 phase 3; rows 8..15 dummy)
#define HS 408          // hbuf sample stride (bf16), channel-last [s][pos*8+ci]
#define LSTR 232        // latb row stride (bf16): 464 B, 16B-aligned, 2-way-bank only

typedef __attribute__((ext_vector_type(8))) __bf16 bf16x8;
typedef __attribute__((ext_vector_type(4))) float f32x4;
typedef __attribute__((ext_vector_type(2))) float f32x2;

// ---------------- Kernel W: swizzle w_fc (392x224 fp32) into bf16 MFMA B-fragments ----------
// wb[((tile*7 + kt)*64 + lane)*8 + j] = bf16(w_fc[n][k]), n = tile*16 + (lane&15),
// k = kt*32 + (lane>>4)*8 + j.  Tiles 0..24 (N padded 392->400 with zeros).
// Also writes aux[8] = {cos,sin}(0.5*params[q]) with the SAME __cosf/__sinf intrinsics ->
// bit-identical phase-1 results.
__global__ void wconv_kernel(const float* __restrict__ w_fc, const float* __restrict__ params,
                             __bf16* __restrict__ wb, float* __restrict__ aux) {
  int tile = blockIdx.x;      // 0..24
  int kt   = blockIdx.y;      // 0..6
  int lane = threadIdx.x;     // 0..63
  int n  = tile * 16 + (lane & 15);
  int k0 = kt * 32 + (lane >> 4) * 8;
  bf16x8 v;
  if (n < 392) {
    const float* src = w_fc + (size_t)n * 224 + k0;
    float4 f0 = *(const float4*)(src);
    float4 f1 = *(const float4*)(src + 4);
    v[0] = (__bf16)f0.x; v[1] = (__bf16)f0.y; v[2] = (__bf16)f0.z; v[3] = (__bf16)f0.w;
    v[4] = (__bf16)f1.x; v[5] = (__bf16)f1.y; v[6] = (__bf16)f1.z; v[7] = (__bf16)f1.w;
  } else {
    #pragma unroll
    for (int j = 0; j < 8; ++j) v[j] = (__bf16)0.f;
  }
  *(bf16x8*)(wb + ((size_t)(tile * 7 + kt) * 64 + lane) * 8) = v;
  if (tile == 0 && kt == 0 && lane < 4) {
    float hp = 0.5f * params[lane];
    aux[2 * lane]     = __cosf(hp);
    aux[2 * lane + 1] = __sinf(hp);
  }
}

// ---------------- Fused kernel: one block = 8 samples, 512 threads = 8 waves ----------------
// Turnover variant of the PROVEN r5 kernel. Residency unchanged (4 blk/CU, 32 waves/CU at
// t=0), but grid 2048 > 1024 resident -> second generation's loads overlap first's drain.
// ZERO-DELTA numerics: waves 0..3 run r5's phases 0-2 VERBATIM (2 samples/wave, samples
// 0..7); waves 4..7 only zero-fill latb rows 8..15. Phase 3 is VERBATIM r5 (full 16-row
// MFMA, no aliasing, no new guards) — D rows 8..15 derive from zero latents, land in hbuf
// rows 8..15, never read. Phase 4 verbatim r5 math over samples 0..7. r6's failed variant
// (1-sample phases + m&7 aliasing + kq guard) is fully avoided.
// HARD CONSTRAINTS: VGPR <= 64 (r4 spill lesson), regular row-contiguous stores (r1 lesson).
__global__ __launch_bounds__(512, 8) void fused_kernel(
    const float* __restrict__ x,
    const __bf16* __restrict__ wb, const float* __restrict__ aux,
    const float* __restrict__ w_lat, const float* __restrict__ b_lat,
    const float* __restrict__ b_fc,
    const float* __restrict__ w_d1, const float* __restrict__ b_d1,
    const float* __restrict__ w_d2, const float* __restrict__ b_d2,
    float* __restrict__ out, int B)
{
  __shared__ __align__(16) __bf16 latb[SR * LSTR];  // 7424 B (rows 8..15 zero-filled)
  __shared__ __align__(16) __bf16 hbuf[SR * HS];    // 13056 B (rows 8..15 write-only dummy)
  __shared__ __align__(16) float qfs[G * 4];        // means, then <Z_q>; wave-private regions
  __shared__ __align__(16) float wd1t[128];         // wd1t[p*32 + ci*4 + co] = w_d1[ci*16+co*4+p]
  __shared__ __align__(16) float wd2[16];
  __shared__ __align__(16) float bd1[4];
  const int t = threadIdx.x;
  const int wv = t >> 6;         // 0..7
  const int lane = t & 63;
  const int s0g = blockIdx.x * G;
  if (s0g >= B) return;

  if (t < 128) {
    int ci = t >> 4, co = (t >> 2) & 3, p = t & 3;
    wd1t[p * 32 + ci * 4 + co] = w_d1[t];
  }
  else if (t < 144) wd2[t - 128] = w_d2[t - 128];
  else if (t < 148) bd1[t - 144] = b_d1[t - 144];

  if (wv < 4) {
    // ---- Phase 0 (wave-local, VERBATIM r5): quadrant sums for samples wv*2, wv*2+1.
    {
      const float* xb = x + (size_t)(s0g + wv * 2) * 784;
      f32x4 vb[2][4];
      #pragma unroll
      for (int smp = 0; smp < 2; ++smp)
        #pragma unroll
        for (int it = 0; it < 4; ++it) {
          int i4 = lane + it * 64;
          if (i4 < 196)
            vb[smp][it] = __builtin_nontemporal_load((const f32x4*)(xb + smp * 784 + i4 * 4));
          else
            vb[smp][it] = (f32x4){0.f, 0.f, 0.f, 0.f};
        }
      float acc[2][4];   // [smp][quad: TL,TR,BL,BR]
      #pragma unroll
      for (int i = 0; i < 2; ++i)
        #pragma unroll
        for (int q = 0; q < 4; ++q) acc[i][q] = 0.f;
      #pragma unroll
      for (int it = 0; it < 4; ++it) {
        int i4 = lane + it * 64;
        int base = i4 * 4;
        int r = base / 28;
        int cb = base - r * 28;          // float4 never crosses a row (28 % 4 == 0)
        float bt = (r >= 14) ? 1.f : 0.f;
        float tp = 1.f - bt;             // i4 >= 196 lanes loaded zeros, weights irrelevant
        float w0[4], w1[4], w2[4], w3[4];
        #pragma unroll
        for (int e = 0; e < 4; ++e) {
          float lf = ((cb + e) < 14) ? 1.f : 0.f;
          float rf = 1.f - lf;
          w0[e] = tp * lf; w1[e] = tp * rf; w2[e] = bt * lf; w3[e] = bt * rf;
        }
        #pragma unroll
        for (int smp = 0; smp < 2; ++smp) {
          f32x4 v = vb[smp][it];
          #pragma unroll
          for (int e = 0; e < 4; ++e) {
            acc[smp][0] = fmaf(v[e], w0[e], acc[smp][0]);
            acc[smp][1] = fmaf(v[e], w1[e], acc[smp][1]);
            acc[smp][2] = fmaf(v[e], w2[e], acc[smp][2]);
            acc[smp][3] = fmaf(v[e], w3[e], acc[smp][3]);
          }
        }
      }
      #pragma unroll
      for (int smp = 0; smp < 2; ++smp)
        #pragma unroll
        for (int q = 0; q < 4; ++q)
          #pragma unroll
          for (int o = 32; o > 0; o >>= 1)
            acc[smp][q] += __shfl_down(acc[smp][q], o, 64);
      if (lane == 0) {
        const float inv = 1.f / 196.f;
        #pragma unroll
        for (int smp = 0; smp < 2; ++smp) {
          float4 o;
          o.x = acc[smp][0] * inv; o.y = acc[smp][1] * inv;
          o.z = acc[smp][2] * inv; o.w = acc[smp][3] * inv;
          *(float4*)(qfs + (wv * 2 + smp) * 4) = o;
        }
      }
    }
    // no barrier: phases 0-2 stay within the wave (DS ops are in-order per wave)

    // ---- Phase 1 (wave-local, ALL 64 lanes, VERBATIM r5): 16 lanes per sample;
    // lane-groups 2,3 duplicate groups 0,1 so shuffles run with full exec mask.
    {
      const int sub = lane >> 4;          // 0..3
      const int i   = lane & 15;          // amplitude index; qubit q <-> bit (3-q)
      const int s   = wv * 2 + (sub & 1); // groups 0/2 -> sample 0, 1/3 -> sample 1
      float4 mn = *(const float4*)(qfs + s * 4);
      float c_[4], s_[4];
      c_[0] = __cosf(0.5f * mn.x); s_[0] = __sinf(0.5f * mn.x);
      c_[1] = __cosf(0.5f * mn.y); s_[1] = __sinf(0.5f * mn.y);
      c_[2] = __cosf(0.5f * mn.z); s_[2] = __sinf(0.5f * mn.z);
      c_[3] = __cosf(0.5f * mn.w); s_[3] = __sinf(0.5f * mn.w);
      float re = (((i >> 3) & 1) ? s_[0] : c_[0]) * (((i >> 2) & 1) ? s_[1] : c_[1])
               * (((i >> 1) & 1) ? s_[2] : c_[2]) * ((i & 1) ? s_[3] : c_[3]);
      float im = 0.f;
      #pragma unroll
      for (int q = 0; q < 4; ++q) {
        float cp = aux[2 * q], sp = aux[2 * q + 1];   // precomputed in wconv, bit-identical
        int qb = 3 - q;
        float sg = ((i >> qb) & 1) ? sp : -sp;     // exp(+-i p/2)
        float r0 = re, i0 = im;
        re = r0 * cp - i0 * sg;
        im = r0 * sg + i0 * cp;
        int cm = 1 << qb;
        int tm = 1 << (3 - ((q + 1) & 3));
        int srcI = (i & cm) ? (i ^ tm) : i;        // CNOT: new[i] = old[i^tm] if control set
        int srcLane = (lane & ~15) | srcI;
        re = __shfl(re, srcLane, 64);
        im = __shfl(im, srcLane, 64);
      }
      float p = re * re + im * im;
      float z[4];
      #pragma unroll
      for (int q = 0; q < 4; ++q) {
        int qb = 3 - q;
        float v = ((i >> qb) & 1) ? -p : p;
        v += __shfl_xor(v, 1, 16);
        v += __shfl_xor(v, 2, 16);
        v += __shfl_xor(v, 4, 16);
        v += __shfl_xor(v, 8, 16);
        z[q] = v;
      }
      if (sub < 2 && i < 4) {             // guard only the write; shuffles are done
        float zv = (i == 0) ? z[0] : (i == 1) ? z[1] : (i == 2) ? z[2] : z[3];
        qfs[s * 4 + i] = zv;
      }
    }

    // ---- Phase 2 (wave-local, VERBATIM r5): latent -> bf16 LDS rows 0..7
    #pragma unroll
    for (int sl = 0; sl < 2; ++sl) {
      int s = wv * 2 + sl;
      float4 q4 = *(const float4*)(qfs + s * 4);
      for (int j = lane; j < 224; j += 64) {
        float4 w = *(const float4*)(w_lat + j * 4);
        float a = b_lat[j];
        a = fmaf(q4.x, w.x, a);
        a = fmaf(q4.y, w.y, a);
        a = fmaf(q4.z, w.z, a);
        a = fmaf(q4.w, w.w, a);
        latb[s * LSTR + j] = (__bf16)fmaxf(a, 0.f);
      }
    }
  } else {
    // ---- Waves 4..7: zero-fill latb rows 8..15 (dummy MFMA rows; D rows 8..15 discarded)
    #pragma unroll
    for (int sl = 0; sl < 2; ++sl) {
      int rr = 8 + (wv - 4) * 2 + sl;
      for (int j = lane; j < 224; j += 64) latb[rr * LSTR + j] = (__bf16)0.f;
    }
  }
  __syncthreads();

  // ---- Phase 3 (VERBATIM r5): MFMA over 16 rows. wave wv handles tiles wv, wv+8, wv+16(,+24).
  // D written channel-last: j -> (ci = j/49, pos = j%49), hbuf[s][pos*8 + ci]; rows 8..15 are
  // zero-latent dummies, written but never read.
  {
    const int m = lane & 15;       // A-row (sample) AND B/D-col (n) index
    const int kq = lane >> 4;      // k-quad
    const __bf16* arow = latb + m * LSTR + kq * 8;
    for (int tile = wv; tile < 25; tile += 8) {
      f32x4 acc = {0.f, 0.f, 0.f, 0.f};
      const bf16x8* bp = (const bf16x8*)(wb + ((size_t)(tile * 7) * 64 + lane) * 8);
      #pragma unroll
      for (int kt = 0; kt < 7; ++kt) {
        bf16x8 a = *(const bf16x8*)(arow + kt * 32);
        bf16x8 b = bp[kt * 64];
        acc = __builtin_amdgcn_mfma_f32_16x16x32_bf16(a, b, acc, 0, 0, 0);
      }
      int j = tile * 16 + m;
      if (j < 392) {
        float bf = b_fc[j];
        int ci = j / 49;
        int off = (j - ci * 49) * 8 + ci;
        #pragma unroll
        for (int r = 0; r < 4; ++r)
          hbuf[(kq * 4 + r) * HS + off] = (__bf16)fmaxf(acc[r] + bf, 0.f);
      }
    }
  }
  __syncthreads();

  // ---- Phase 4 (VERBATIM r5 math, G=8 bound): one thread = one 2x2 output quarter;
  // h via ONE ds_read_b128, wd1 via broadcast b128 reads of wd1t, wd2/b1 in regs.
  // f32x2 regular row-contiguous stores.
  {
    f32x4 w2v[4];
    #pragma unroll
    for (int co = 0; co < 4; ++co) w2v[co] = *(const f32x4*)(wd2 + co * 4);
    f32x4 b1v = *(const f32x4*)(bd1);
    const float bd2v = b_d2[0];
    for (int v = t; v < G * 196; v += 512) {
      int s = v / 196;
      int p = v - s * 196;
      int Y = p / 14;
      int X = p - Y * 14;
      int y = Y >> 1, ey = Y & 1, xx = X >> 1, ex = X & 1;
      int pp = ey * 2 + ex;
      bf16x8 hb = *(const bf16x8*)(hbuf + s * HS + (y * 7 + xx) * 8);
      float o1[4];
      #pragma unroll
      for (int co = 0; co < 4; ++co) o1[co] = b1v[co];
      #pragma unroll
      for (int ci = 0; ci < 8; ++ci) {
        f32x4 w4 = *(const f32x4*)(wd1t + pp * 32 + ci * 4);   // broadcast (4 addrs/wave)
        float h = (float)hb[ci];
        #pragma unroll
        for (int co = 0; co < 4; ++co) o1[co] = fmaf(h, w4[co], o1[co]);
      }
      #pragma unroll
      for (int co = 0; co < 4; ++co) o1[co] = fmaxf(o1[co], 0.f);
      size_t basep = (size_t)(s0g + s) * 784;
      #pragma unroll
      for (int dy = 0; dy < 2; ++dy) {
        float v0 = bd2v, v1 = bd2v;
        #pragma unroll
        for (int co = 0; co < 4; ++co) {
          v0 = fmaf(o1[co], w2v[co][dy * 2 + 0], v0);
          v1 = fmaf(o1[co], w2v[co][dy * 2 + 1], v1);
        }
        f32x2 o;
        o[0] = 1.f / (1.f + __expf(-v0));
        o[1] = 1.f / (1.f + __expf(-v1));
        *(f32x2*)(out + basep + (size_t)(2 * Y + dy) * 28 + 2 * X) = o;
      }
    }
  }
}

extern "C" void kernel_launch(void* const* d_in, const int* in_sizes, int n_in,
                              void* d_out, int out_size, void* d_ws, size_t ws_size,
                              hipStream_t stream) {
  const float* x          = (const float*)d_in[0];
  const float* var_params = (const float*)d_in[1];
  const float* w_lat      = (const float*)d_in[2];
  const float* b_lat      = (const float*)d_in[3];
  const float* w_fc       = (const float*)d_in[4];
  const float* b_fc       = (const float*)d_in[5];
  const float* w_d1       = (const float*)d_in[6];
  const float* b_d1       = (const float*)d_in[7];
  const float* w_d2       = (const float*)d_in[8];
  const float* b_d2       = (const float*)d_in[9];
  float* out = (float*)d_out;

  __bf16* wb = (__bf16*)d_ws;   // 25*7*64*8 bf16 = 179200 B of swizzled w_fc fragments
  float* aux = (float*)((char*)d_ws + (size_t)25 * 7 * 64 * 8 * sizeof(__bf16));  // sincos(params/2)

  int B = in_sizes[0] / 784;
  wconv_kernel<<<dim3(25, 7), 64, 0, stream>>>(w_fc, var_params, wb, aux);
  fused_kernel<<<(B + G - 1) / G, 512, 0, stream>>>(
      x, wb, aux, w_lat, b_lat, b_fc, w_d1, b_d1, w_d2, b_d2, out, B);
}

// Round 8
// 129.060 us; speedup vs baseline: 1.1225x; 1.1225x over previous
//
#include <hip/hip_runtime.h>
#include <math.h>

#define G 16
#define HS 408          // hbuf sample stride (bf16), channel-last [s][pos*8+ci]; 816 B/sample,
                        // 16B-aligned so each phase-4 h-read is a single ds_read_b128
#define LSTR 232        // latb row stride (bf16): 464 B, 16B-aligned, 2-way-bank only

typedef __attribute__((ext_vector_type(8))) __bf16 bf16x8;
typedef __attribute__((ext_vector_type(4))) float f32x4;
typedef __attribute__((ext_vector_type(2))) float f32x2;

// ---------------- Kernel W: swizzle w_fc (392x224 fp32) into bf16 MFMA B-fragments ----------
// wb[((tile*7 + kt)*64 + lane)*8 + j] = bf16(w_fc[n][k]), n = tile*16 + (lane&15),
// k = kt*32 + (lane>>4)*8 + j.  Tiles 0..24 (N padded 392->400 with zeros).
// Also writes aux[8] = {cos,sin}(0.5*params[q]) with the SAME __cosf/__sinf intrinsics ->
// bit-identical phase-1 results.
__global__ void wconv_kernel(const float* __restrict__ w_fc, const float* __restrict__ params,
                             __bf16* __restrict__ wb, float* __restrict__ aux) {
  int tile = blockIdx.x;      // 0..24
  int kt   = blockIdx.y;      // 0..6
  int lane = threadIdx.x;     // 0..63
  int n  = tile * 16 + (lane & 15);
  int k0 = kt * 32 + (lane >> 4) * 8;
  bf16x8 v;
  if (n < 392) {
    const float* src = w_fc + (size_t)n * 224 + k0;
    float4 f0 = *(const float4*)(src);
    float4 f1 = *(const float4*)(src + 4);
    v[0] = (__bf16)f0.x; v[1] = (__bf16)f0.y; v[2] = (__bf16)f0.z; v[3] = (__bf16)f0.w;
    v[4] = (__bf16)f1.x; v[5] = (__bf16)f1.y; v[6] = (__bf16)f1.z; v[7] = (__bf16)f1.w;
  } else {
    #pragma unroll
    for (int j = 0; j < 8; ++j) v[j] = (__bf16)0.f;
  }
  *(bf16x8*)(wb + ((size_t)(tile * 7 + kt) * 64 + lane) * 8) = v;
  if (tile == 0 && kt == 0 && lane < 4) {
    float hp = 0.5f * params[lane];
    aux[2 * lane]     = __cosf(hp);
    aux[2 * lane + 1] = __sinf(hp);
  }
}

// ---------------- Fused kernel: one block = 16 samples, 512 threads = 8 waves ----------------
// PROVEN STRUCTURE (r5, 133.7 us total): grid 1024 x 8 waves = 32 waves/CU full residency.
// Structural departures all lost: r1/r3 (pipeline @ half residency), r7 (G=8 turnover with
// idle waves). This round, two bit-identical micro-opts only:
//  (1) x loads are PLAIN (not nontemporal): r7's FETCH=26MB < 51.4MB input proved x persists
//      in the 256MB L3 across harness iterations — nt hints fight that retention.
//  (2) phase-4 index math is incremental (exact same (s,Y,X) sequence, ~1/3 the VALU).
// HARD CONSTRAINTS: VGPR <= 64 under launch_bounds(512,8) (r4 spill lesson), regular
// row-contiguous f32x2 stores (r1 lesson).
__global__ __launch_bounds__(512, 8) void fused_kernel(
    const float* __restrict__ x,
    const __bf16* __restrict__ wb, const float* __restrict__ aux,
    const float* __restrict__ w_lat, const float* __restrict__ b_lat,
    const float* __restrict__ b_fc,
    const float* __restrict__ w_d1, const float* __restrict__ b_d1,
    const float* __restrict__ w_d2, const float* __restrict__ b_d2,
    float* __restrict__ out, int B)
{
  __shared__ __align__(16) __bf16 latb[G * LSTR];   // 7424 B
  __shared__ __align__(16) __bf16 hbuf[G * HS];     // 13056 B, channel-last: [s][pos49][ci8]
  __shared__ __align__(16) float qfs[G * 4];        // means, then <Z_q>; wave-private regions
  __shared__ __align__(16) float wd1t[128];         // wd1t[p*32 + ci*4 + co] = w_d1[ci*16+co*4+p]
  __shared__ __align__(16) float wd2[16];
  __shared__ __align__(16) float bd1[4];
  const int t = threadIdx.x;
  const int wv = t >> 6;         // 0..7
  const int lane = t & 63;
  const int s0g = blockIdx.x * G;
  if (s0g >= B) return;

  if (t < 128) {
    int ci = t >> 4, co = (t >> 2) & 3, p = t & 3;
    wd1t[p * 32 + ci * 4 + co] = w_d1[t];
  }
  else if (t < 144) wd2[t - 128] = w_d2[t - 128];
  else if (t < 148) bd1[t - 144] = b_d1[t - 144];

  // ---- Phase 0 (wave-local): quadrant sums for samples wv*2, wv*2+1. PLAIN loads (L3-hot).
  {
    const float* xb = x + (size_t)(s0g + wv * 2) * 784;
    f32x4 vb[2][4];
    #pragma unroll
    for (int smp = 0; smp < 2; ++smp)
      #pragma unroll
      for (int it = 0; it < 4; ++it) {
        int i4 = lane + it * 64;
        if (i4 < 196)
          vb[smp][it] = *(const f32x4*)(xb + smp * 784 + i4 * 4);
        else
          vb[smp][it] = (f32x4){0.f, 0.f, 0.f, 0.f};
      }
    float acc[2][4];   // [smp][quad: TL,TR,BL,BR]
    #pragma unroll
    for (int i = 0; i < 2; ++i)
      #pragma unroll
      for (int q = 0; q < 4; ++q) acc[i][q] = 0.f;
    #pragma unroll
    for (int it = 0; it < 4; ++it) {
      int i4 = lane + it * 64;
      int base = i4 * 4;
      int r = base / 28;
      int cb = base - r * 28;          // float4 never crosses a row (28 % 4 == 0)
      float bt = (r >= 14) ? 1.f : 0.f;
      float tp = 1.f - bt;             // i4 >= 196 lanes loaded zeros, weights irrelevant
      float w0[4], w1[4], w2[4], w3[4];
      #pragma unroll
      for (int e = 0; e < 4; ++e) {
        float lf = ((cb + e) < 14) ? 1.f : 0.f;
        float rf = 1.f - lf;
        w0[e] = tp * lf; w1[e] = tp * rf; w2[e] = bt * lf; w3[e] = bt * rf;
      }
      #pragma unroll
      for (int smp = 0; smp < 2; ++smp) {
        f32x4 v = vb[smp][it];
        #pragma unroll
        for (int e = 0; e < 4; ++e) {
          acc[smp][0] = fmaf(v[e], w0[e], acc[smp][0]);
          acc[smp][1] = fmaf(v[e], w1[e], acc[smp][1]);
          acc[smp][2] = fmaf(v[e], w2[e], acc[smp][2]);
          acc[smp][3] = fmaf(v[e], w3[e], acc[smp][3]);
        }
      }
    }
    #pragma unroll
    for (int smp = 0; smp < 2; ++smp)
      #pragma unroll
      for (int q = 0; q < 4; ++q)
        #pragma unroll
        for (int o = 32; o > 0; o >>= 1)
          acc[smp][q] += __shfl_down(acc[smp][q], o, 64);
    if (lane == 0) {
      const float inv = 1.f / 196.f;
      #pragma unroll
      for (int smp = 0; smp < 2; ++smp) {
        float4 o;
        o.x = acc[smp][0] * inv; o.y = acc[smp][1] * inv;
        o.z = acc[smp][2] * inv; o.w = acc[smp][3] * inv;
        *(float4*)(qfs + (wv * 2 + smp) * 4) = o;
      }
    }
  }
  // no barrier: phases 0-2 stay within the wave (DS ops are in-order per wave)

  // ---- Phase 1 (wave-local, lane-parallel, ALL 64 lanes): 16 lanes per sample;
  // lane-groups 2,3 duplicate groups 0,1 so shuffles run with full exec mask.
  {
    const int sub = lane >> 4;          // 0..3
    const int i   = lane & 15;          // amplitude index; qubit q <-> bit (3-q)
    const int s   = wv * 2 + (sub & 1); // groups 0/2 -> sample 0, 1/3 -> sample 1
    float4 mn = *(const float4*)(qfs + s * 4);
    float c_[4], s_[4];
    c_[0] = __cosf(0.5f * mn.x); s_[0] = __sinf(0.5f * mn.x);
    c_[1] = __cosf(0.5f * mn.y); s_[1] = __sinf(0.5f * mn.y);
    c_[2] = __cosf(0.5f * mn.z); s_[2] = __sinf(0.5f * mn.z);
    c_[3] = __cosf(0.5f * mn.w); s_[3] = __sinf(0.5f * mn.w);
    float re = (((i >> 3) & 1) ? s_[0] : c_[0]) * (((i >> 2) & 1) ? s_[1] : c_[1])
             * (((i >> 1) & 1) ? s_[2] : c_[2]) * ((i & 1) ? s_[3] : c_[3]);
    float im = 0.f;
    #pragma unroll
    for (int q = 0; q < 4; ++q) {
      float cp = aux[2 * q], sp = aux[2 * q + 1];   // precomputed in wconv, bit-identical
      int qb = 3 - q;
      float sg = ((i >> qb) & 1) ? sp : -sp;     // exp(+-i p/2)
      float r0 = re, i0 = im;
      re = r0 * cp - i0 * sg;
      im = r0 * sg + i0 * cp;
      int cm = 1 << qb;
      int tm = 1 << (3 - ((q + 1) & 3));
      int srcI = (i & cm) ? (i ^ tm) : i;        // CNOT: new[i] = old[i^tm] if control set
      int srcLane = (lane & ~15) | srcI;
      re = __shfl(re, srcLane, 64);
      im = __shfl(im, srcLane, 64);
    }
    float p = re * re + im * im;
    float z[4];
    #pragma unroll
    for (int q = 0; q < 4; ++q) {
      int qb = 3 - q;
      float v = ((i >> qb) & 1) ? -p : p;
      v += __shfl_xor(v, 1, 16);
      v += __shfl_xor(v, 2, 16);
      v += __shfl_xor(v, 4, 16);
      v += __shfl_xor(v, 8, 16);
      z[q] = v;
    }
    if (sub < 2 && i < 4) {             // guard only the write; shuffles are done
      float zv = (i == 0) ? z[0] : (i == 1) ? z[1] : (i == 2) ? z[2] : z[3];
      qfs[s * 4 + i] = zv;
    }
  }

  // ---- Phase 2 (wave-local): latent[s][j] = relu(qf[s] . w_lat[j] + b_lat[j]) -> bf16 LDS
  #pragma unroll
  for (int sl = 0; sl < 2; ++sl) {
    int s = wv * 2 + sl;
    float4 q4 = *(const float4*)(qfs + s * 4);
    for (int j = lane; j < 224; j += 64) {
      float4 w = *(const float4*)(w_lat + j * 4);
      float a = b_lat[j];
      a = fmaf(q4.x, w.x, a);
      a = fmaf(q4.y, w.y, a);
      a = fmaf(q4.z, w.z, a);
      a = fmaf(q4.w, w.w, a);
      latb[s * LSTR + j] = (__bf16)fmaxf(a, 0.f);
    }
  }
  __syncthreads();

  // ---- Phase 3: MFMA. wave wv handles N-tiles wv, wv+8, wv+16, (wv+24).
  // D written channel-last: j -> (ci = j/49, pos = j%49), hbuf[s][pos*8 + ci].
  {
    const int m = lane & 15;       // A-row (sample) AND B/D-col (n) index
    const int kq = lane >> 4;      // k-quad
    const __bf16* arow = latb + m * LSTR + kq * 8;
    for (int tile = wv; tile < 25; tile += 8) {
      f32x4 acc = {0.f, 0.f, 0.f, 0.f};
      const bf16x8* bp = (const bf16x8*)(wb + ((size_t)(tile * 7) * 64 + lane) * 8);
      #pragma unroll
      for (int kt = 0; kt < 7; ++kt) {
        bf16x8 a = *(const bf16x8*)(arow + kt * 32);
        bf16x8 b = bp[kt * 64];
        acc = __builtin_amdgcn_mfma_f32_16x16x32_bf16(a, b, acc, 0, 0, 0);
      }
      int j = tile * 16 + m;
      if (j < 392) {
        float bf = b_fc[j];
        int ci = j / 49;
        int off = (j - ci * 49) * 8 + ci;
        #pragma unroll
        for (int r = 0; r < 4; ++r)
          hbuf[(kq * 4 + r) * HS + off] = (__bf16)fmaxf(acc[r] + bf, 0.f);
      }
    }
  }
  __syncthreads();

  // ---- Phase 4: one thread = one 2x2 output quarter; h via ONE ds_read_b128, wd1 via
  // broadcast b128 reads of wd1t, wd2/b1 in regs. Incremental (s,Y,X) indexing: v = t + i*512
  // with 512 = 2*196 + 120, 120 = 8*14 + 8 -> s += 2, Y += 8, X += 8 and two carries;
  // identical index sequence to the division form -> identical addresses, bit-identical output.
  {
    f32x4 w2v[4];
    #pragma unroll
    for (int co = 0; co < 4; ++co) w2v[co] = *(const f32x4*)(wd2 + co * 4);
    f32x4 b1v = *(const f32x4*)(bd1);
    const float bd2v = b_d2[0];
    int s, Y, X;
    {
      int v0 = t;
      s = v0 / 196;
      int p = v0 - s * 196;
      Y = p / 14;
      X = p - Y * 14;
    }
    for (int v = t; v < G * 196; v += 512) {
      int y = Y >> 1, ey = Y & 1, xx = X >> 1, ex = X & 1;
      int pp = ey * 2 + ex;
      bf16x8 hb = *(const bf16x8*)(hbuf + s * HS + (y * 7 + xx) * 8);
      float o1[4];
      #pragma unroll
      for (int co = 0; co < 4; ++co) o1[co] = b1v[co];
      #pragma unroll
      for (int ci = 0; ci < 8; ++ci) {
        f32x4 w4 = *(const f32x4*)(wd1t + pp * 32 + ci * 4);   // broadcast (4 addrs/wave)
        float h = (float)hb[ci];
        #pragma unroll
        for (int co = 0; co < 4; ++co) o1[co] = fmaf(h, w4[co], o1[co]);
      }
      #pragma unroll
      for (int co = 0; co < 4; ++co) o1[co] = fmaxf(o1[co], 0.f);
      size_t basep = (size_t)(s0g + s) * 784;
      #pragma unroll
      for (int dy = 0; dy < 2; ++dy) {
        float v0 = bd2v, v1 = bd2v;
        #pragma unroll
        for (int co = 0; co < 4; ++co) {
          v0 = fmaf(o1[co], w2v[co][dy * 2 + 0], v0);
          v1 = fmaf(o1[co], w2v[co][dy * 2 + 1], v1);
        }
        f32x2 o;
        o[0] = 1.f / (1.f + __expf(-v0));
        o[1] = 1.f / (1.f + __expf(-v1));
        *(f32x2*)(out + basep + (size_t)(2 * Y + dy) * 28 + 2 * X) = o;
      }
      // advance to v + 512: maintain v = s*196 + Y*14 + X, 0<=X<14, 0<=Y<14
      s += 2; Y += 8; X += 8;
      if (X >= 14) { X -= 14; Y += 1; }
      if (Y >= 14) { Y -= 14; s += 1; }
    }
  }
}

extern "C" void kernel_launch(void* const* d_in, const int* in_sizes, int n_in,
                              void* d_out, int out_size, void* d_ws, size_t ws_size,
                              hipStream_t stream) {
  const float* x          = (const float*)d_in[0];
  const float* var_params = (const float*)d_in[1];
  const float* w_lat      = (const float*)d_in[2];
  const float* b_lat      = (const float*)d_in[3];
  const float* w_fc       = (const float*)d_in[4];
  const float* b_fc       = (const float*)d_in[5];
  const float* w_d1       = (const float*)d_in[6];
  const float* b_d1       = (const float*)d_in[7];
  const float* w_d2       = (const float*)d_in[8];
  const float* b_d2       = (const float*)d_in[9];
  float* out = (float*)d_out;

  __bf16* wb = (__bf16*)d_ws;   // 25*7*64*8 bf16 = 179200 B of swizzled w_fc fragments
  float* aux = (float*)((char*)d_ws + (size_t)25 * 7 * 64 * 8 * sizeof(__bf16));  // sincos(params/2)

  int B = in_sizes[0] / 784;
  wconv_kernel<<<dim3(25, 7), 64, 0, stream>>>(w_fc, var_params, wb, aux);
  fused_kernel<<<(B + G - 1) / G, 512, 0, stream>>>(
      x, wb, aux, w_lat, b_lat, b_fc, w_d1, b_d1, w_d2, b_d2, out, B);
}

// Round 9
// 128.439 us; speedup vs baseline: 1.1280x; 1.0048x over previous
//
#include <hip/hip_runtime.h>
#include <math.h>

#define G 16
#define HS 408          // hbuf sample stride (bf16), channel-last [s][pos*8+ci]; 816 B/sample,
                        // 16B-aligned so each phase-4 h-read is a single ds_read_b128
#define LSTR 232        // latb row stride (bf16): 464 B, 16B-aligned, 2-way-bank only

typedef __attribute__((ext_vector_type(8))) __bf16 bf16x8;
typedef __attribute__((ext_vector_type(4))) float f32x4;
typedef __attribute__((ext_vector_type(2))) float f32x2;

// ---------------- Kernel W: swizzle w_fc (392x224 fp32) into bf16 MFMA B-fragments ----------
// wb[((tile*7 + kt)*64 + lane)*8 + j] = bf16(w_fc[n][k]), n = tile*16 + (lane&15),
// k = kt*32 + (lane>>4)*8 + j.  Tiles 0..24 (N padded 392->400 with zeros).
// Also writes aux[8] = {cos,sin}(0.5*params[q]) with the SAME __cosf/__sinf intrinsics ->
// bit-identical phase-1 results.
__global__ void wconv_kernel(const float* __restrict__ w_fc, const float* __restrict__ params,
                             __bf16* __restrict__ wb, float* __restrict__ aux) {
  int tile = blockIdx.x;      // 0..24
  int kt   = blockIdx.y;      // 0..6
  int lane = threadIdx.x;     // 0..63
  int n  = tile * 16 + (lane & 15);
  int k0 = kt * 32 + (lane >> 4) * 8;
  bf16x8 v;
  if (n < 392) {
    const float* src = w_fc + (size_t)n * 224 + k0;
    float4 f0 = *(const float4*)(src);
    float4 f1 = *(const float4*)(src + 4);
    v[0] = (__bf16)f0.x; v[1] = (__bf16)f0.y; v[2] = (__bf16)f0.z; v[3] = (__bf16)f0.w;
    v[4] = (__bf16)f1.x; v[5] = (__bf16)f1.y; v[6] = (__bf16)f1.z; v[7] = (__bf16)f1.w;
  } else {
    #pragma unroll
    for (int j = 0; j < 8; ++j) v[j] = (__bf16)0.f;
  }
  *(bf16x8*)(wb + ((size_t)(tile * 7 + kt) * 64 + lane) * 8) = v;
  if (tile == 0 && kt == 0 && lane < 4) {
    float hp = 0.5f * params[lane];
    aux[2 * lane]     = __cosf(hp);
    aux[2 * lane + 1] = __sinf(hp);
  }
}

// ---------------- Fused kernel: one block = 16 samples, 512 threads = 8 waves ----------------
// PROVEN STRUCTURE (r8, 129.06 us total): grid 1024 x 8 waves = 32 waves/CU full residency,
// plain L3-hot x loads, incremental phase-4 indexing. All structural departures lost
// (r1/r3/r7); remaining gains are VALU-issue cuts. This round:
//  (1) sigmoid via __builtin_amdgcn_rcpf: 1/(1+e) without fast-math emits the full
//      div_scale/div_fmas/div_fixup sequence (~10 slots x 24/thread); v_rcp_f32 is 1 slot,
//      ~1ulp (error ~1e-7 << 1.09e-2 threshold).
//  (2) phase-0 horizontal-add restructure: each float4 is wholly in one column-half except
//      cb==12 -> (v0+v1)+(v2+v3), 2 selects, 4 FMAs (~22 slots/it vs ~52). fp32 reorder
//      noise absorbed by bf16 rounding.
// HARD CONSTRAINTS: VGPR <= 64 under launch_bounds(512,8) (r4 spill lesson), regular
// row-contiguous f32x2 stores (r1 lesson).
__global__ __launch_bounds__(512, 8) void fused_kernel(
    const float* __restrict__ x,
    const __bf16* __restrict__ wb, const float* __restrict__ aux,
    const float* __restrict__ w_lat, const float* __restrict__ b_lat,
    const float* __restrict__ b_fc,
    const float* __restrict__ w_d1, const float* __restrict__ b_d1,
    const float* __restrict__ w_d2, const float* __restrict__ b_d2,
    float* __restrict__ out, int B)
{
  __shared__ __align__(16) __bf16 latb[G * LSTR];   // 7424 B
  __shared__ __align__(16) __bf16 hbuf[G * HS];     // 13056 B, channel-last: [s][pos49][ci8]
  __shared__ __align__(16) float qfs[G * 4];        // means, then <Z_q>; wave-private regions
  __shared__ __align__(16) float wd1t[128];         // wd1t[p*32 + ci*4 + co] = w_d1[ci*16+co*4+p]
  __shared__ __align__(16) float wd2[16];
  __shared__ __align__(16) float bd1[4];
  const int t = threadIdx.x;
  const int wv = t >> 6;         // 0..7
  const int lane = t & 63;
  const int s0g = blockIdx.x * G;
  if (s0g >= B) return;

  if (t < 128) {
    int ci = t >> 4, co = (t >> 2) & 3, p = t & 3;
    wd1t[p * 32 + ci * 4 + co] = w_d1[t];
  }
  else if (t < 144) wd2[t - 128] = w_d2[t - 128];
  else if (t < 148) bd1[t - 144] = b_d1[t - 144];

  // ---- Phase 0 (wave-local): quadrant sums for samples wv*2, wv*2+1. PLAIN loads (L3-hot).
  // Horizontal-add restructure: float4 at cb in {0,4,8} all-left, {16,20,24} all-right,
  // cb==12 splits (cols 12,13 | 14,15). tp/bt are exact 0/1 factors.
  {
    const float* xb = x + (size_t)(s0g + wv * 2) * 784;
    f32x4 vb[2][4];
    #pragma unroll
    for (int smp = 0; smp < 2; ++smp)
      #pragma unroll
      for (int it = 0; it < 4; ++it) {
        int i4 = lane + it * 64;
        if (i4 < 196)
          vb[smp][it] = *(const f32x4*)(xb + smp * 784 + i4 * 4);
        else
          vb[smp][it] = (f32x4){0.f, 0.f, 0.f, 0.f};
      }
    float acc[2][4];   // [smp][quad: TL,TR,BL,BR]
    #pragma unroll
    for (int i = 0; i < 2; ++i)
      #pragma unroll
      for (int q = 0; q < 4; ++q) acc[i][q] = 0.f;
    #pragma unroll
    for (int it = 0; it < 4; ++it) {
      int i4 = lane + it * 64;
      int base = i4 * 4;
      int r = base / 28;
      int cb = base - r * 28;          // float4 never crosses a row (28 % 4 == 0)
      float bt = (r >= 14) ? 1.f : 0.f;
      float tp = 1.f - bt;             // i4 >= 196 lanes loaded zeros, contribute nothing
      bool leftall = (cb < 12);
      bool split   = (cb == 12);
      #pragma unroll
      for (int smp = 0; smp < 2; ++smp) {
        f32x4 v = vb[smp][it];
        float ls = v[0] + v[1];
        float rs = v[2] + v[3];
        float al = ls + rs;
        float lsum = leftall ? al : (split ? ls : 0.f);
        float rsum = leftall ? 0.f : (split ? rs : al);
        acc[smp][0] = fmaf(lsum, tp, acc[smp][0]);
        acc[smp][1] = fmaf(rsum, tp, acc[smp][1]);
        acc[smp][2] = fmaf(lsum, bt, acc[smp][2]);
        acc[smp][3] = fmaf(rsum, bt, acc[smp][3]);
      }
    }
    #pragma unroll
    for (int smp = 0; smp < 2; ++smp)
      #pragma unroll
      for (int q = 0; q < 4; ++q)
        #pragma unroll
        for (int o = 32; o > 0; o >>= 1)
          acc[smp][q] += __shfl_down(acc[smp][q], o, 64);
    if (lane == 0) {
      const float inv = 1.f / 196.f;
      #pragma unroll
      for (int smp = 0; smp < 2; ++smp) {
        float4 o;
        o.x = acc[smp][0] * inv; o.y = acc[smp][1] * inv;
        o.z = acc[smp][2] * inv; o.w = acc[smp][3] * inv;
        *(float4*)(qfs + (wv * 2 + smp) * 4) = o;
      }
    }
  }
  // no barrier: phases 0-2 stay within the wave (DS ops are in-order per wave)

  // ---- Phase 1 (wave-local, lane-parallel, ALL 64 lanes): 16 lanes per sample;
  // lane-groups 2,3 duplicate groups 0,1 so shuffles run with full exec mask.
  {
    const int sub = lane >> 4;          // 0..3
    const int i   = lane & 15;          // amplitude index; qubit q <-> bit (3-q)
    const int s   = wv * 2 + (sub & 1); // groups 0/2 -> sample 0, 1/3 -> sample 1
    float4 mn = *(const float4*)(qfs + s * 4);
    float c_[4], s_[4];
    c_[0] = __cosf(0.5f * mn.x); s_[0] = __sinf(0.5f * mn.x);
    c_[1] = __cosf(0.5f * mn.y); s_[1] = __sinf(0.5f * mn.y);
    c_[2] = __cosf(0.5f * mn.z); s_[2] = __sinf(0.5f * mn.z);
    c_[3] = __cosf(0.5f * mn.w); s_[3] = __sinf(0.5f * mn.w);
    float re = (((i >> 3) & 1) ? s_[0] : c_[0]) * (((i >> 2) & 1) ? s_[1] : c_[1])
             * (((i >> 1) & 1) ? s_[2] : c_[2]) * ((i & 1) ? s_[3] : c_[3]);
    float im = 0.f;
    #pragma unroll
    for (int q = 0; q < 4; ++q) {
      float cp = aux[2 * q], sp = aux[2 * q + 1];   // precomputed in wconv, bit-identical
      int qb = 3 - q;
      float sg = ((i >> qb) & 1) ? sp : -sp;     // exp(+-i p/2)
      float r0 = re, i0 = im;
      re = r0 * cp - i0 * sg;
      im = r0 * sg + i0 * cp;
      int cm = 1 << qb;
      int tm = 1 << (3 - ((q + 1) & 3));
      int srcI = (i & cm) ? (i ^ tm) : i;        // CNOT: new[i] = old[i^tm] if control set
      int srcLane = (lane & ~15) | srcI;
      re = __shfl(re, srcLane, 64);
      im = __shfl(im, srcLane, 64);
    }
    float p = re * re + im * im;
    float z[4];
    #pragma unroll
    for (int q = 0; q < 4; ++q) {
      int qb = 3 - q;
      float v = ((i >> qb) & 1) ? -p : p;
      v += __shfl_xor(v, 1, 16);
      v += __shfl_xor(v, 2, 16);
      v += __shfl_xor(v, 4, 16);
      v += __shfl_xor(v, 8, 16);
      z[q] = v;
    }
    if (sub < 2 && i < 4) {             // guard only the write; shuffles are done
      float zv = (i == 0) ? z[0] : (i == 1) ? z[1] : (i == 2) ? z[2] : z[3];
      qfs[s * 4 + i] = zv;
    }
  }

  // ---- Phase 2 (wave-local): latent[s][j] = relu(qf[s] . w_lat[j] + b_lat[j]) -> bf16 LDS
  #pragma unroll
  for (int sl = 0; sl < 2; ++sl) {
    int s = wv * 2 + sl;
    float4 q4 = *(const float4*)(qfs + s * 4);
    for (int j = lane; j < 224; j += 64) {
      float4 w = *(const float4*)(w_lat + j * 4);
      float a = b_lat[j];
      a = fmaf(q4.x, w.x, a);
      a = fmaf(q4.y, w.y, a);
      a = fmaf(q4.z, w.z, a);
      a = fmaf(q4.w, w.w, a);
      latb[s * LSTR + j] = (__bf16)fmaxf(a, 0.f);
    }
  }
  __syncthreads();

  // ---- Phase 3: MFMA. wave wv handles N-tiles wv, wv+8, wv+16, (wv+24).
  // D written channel-last: j -> (ci = j/49, pos = j%49), hbuf[s][pos*8 + ci].
  {
    const int m = lane & 15;       // A-row (sample) AND B/D-col (n) index
    const int kq = lane >> 4;      // k-quad
    const __bf16* arow = latb + m * LSTR + kq * 8;
    for (int tile = wv; tile < 25; tile += 8) {
      f32x4 acc = {0.f, 0.f, 0.f, 0.f};
      const bf16x8* bp = (const bf16x8*)(wb + ((size_t)(tile * 7) * 64 + lane) * 8);
      #pragma unroll
      for (int kt = 0; kt < 7; ++kt) {
        bf16x8 a = *(const bf16x8*)(arow + kt * 32);
        bf16x8 b = bp[kt * 64];
        acc = __builtin_amdgcn_mfma_f32_16x16x32_bf16(a, b, acc, 0, 0, 0);
      }
      int j = tile * 16 + m;
      if (j < 392) {
        float bf = b_fc[j];
        int ci = j / 49;
        int off = (j - ci * 49) * 8 + ci;
        #pragma unroll
        for (int r = 0; r < 4; ++r)
          hbuf[(kq * 4 + r) * HS + off] = (__bf16)fmaxf(acc[r] + bf, 0.f);
      }
    }
  }
  __syncthreads();

  // ---- Phase 4: one thread = one 2x2 output quarter; h via ONE ds_read_b128, wd1 via
  // broadcast b128 reads of wd1t, wd2/b1 in regs, incremental (s,Y,X) indexing (r8-proven).
  // Sigmoid via v_rcp_f32 (~1ulp; replaces ~10-slot exact-div sequence x24/thread).
  {
    f32x4 w2v[4];
    #pragma unroll
    for (int co = 0; co < 4; ++co) w2v[co] = *(const f32x4*)(wd2 + co * 4);
    f32x4 b1v = *(const f32x4*)(bd1);
    const float bd2v = b_d2[0];
    int s, Y, X;
    {
      int v0 = t;
      s = v0 / 196;
      int p = v0 - s * 196;
      Y = p / 14;
      X = p - Y * 14;
    }
    for (int v = t; v < G * 196; v += 512) {
      int y = Y >> 1, ey = Y & 1, xx = X >> 1, ex = X & 1;
      int pp = ey * 2 + ex;
      bf16x8 hb = *(const bf16x8*)(hbuf + s * HS + (y * 7 + xx) * 8);
      float o1[4];
      #pragma unroll
      for (int co = 0; co < 4; ++co) o1[co] = b1v[co];
      #pragma unroll
      for (int ci = 0; ci < 8; ++ci) {
        f32x4 w4 = *(const f32x4*)(wd1t + pp * 32 + ci * 4);   // broadcast (4 addrs/wave)
        float h = (float)hb[ci];
        #pragma unroll
        for (int co = 0; co < 4; ++co) o1[co] = fmaf(h, w4[co], o1[co]);
      }
      #pragma unroll
      for (int co = 0; co < 4; ++co) o1[co] = fmaxf(o1[co], 0.f);
      size_t basep = (size_t)(s0g + s) * 784;
      #pragma unroll
      for (int dy = 0; dy < 2; ++dy) {
        float v0 = bd2v, v1 = bd2v;
        #pragma unroll
        for (int co = 0; co < 4; ++co) {
          v0 = fmaf(o1[co], w2v[co][dy * 2 + 0], v0);
          v1 = fmaf(o1[co], w2v[co][dy * 2 + 1], v1);
        }
        f32x2 o;
        o[0] = __builtin_amdgcn_rcpf(1.f + __expf(-v0));
        o[1] = __builtin_amdgcn_rcpf(1.f + __expf(-v1));
        *(f32x2*)(out + basep + (size_t)(2 * Y + dy) * 28 + 2 * X) = o;
      }
      // advance to v + 512: maintain v = s*196 + Y*14 + X, 0<=X<14, 0<=Y<14
      s += 2; Y += 8; X += 8;
      if (X >= 14) { X -= 14; Y += 1; }
      if (Y >= 14) { Y -= 14; s += 1; }
    }
  }
}

extern "C" void kernel_launch(void* const* d_in, const int* in_sizes, int n_in,
                              void* d_out, int out_size, void* d_ws, size_t ws_size,
                              hipStream_t stream) {
  const float* x          = (const float*)d_in[0];
  const float* var_params = (const float*)d_in[1];
  const float* w_lat      = (const float*)d_in[2];
  const float* b_lat      = (const float*)d_in[3];
  const float* w_fc       = (const float*)d_in[4];
  const float* b_fc       = (const float*)d_in[5];
  const float* w_d1       = (const float*)d_in[6];
  const float* b_d1       = (const float*)d_in[7];
  const float* w_d2       = (const float*)d_in[8];
  const float* b_d2       = (const float*)d_in[9];
  float* out = (float*)d_out;

  __bf16* wb = (__bf16*)d_ws;   // 25*7*64*8 bf16 = 179200 B of swizzled w_fc fragments
  float* aux = (float*)((char*)d_ws + (size_t)25 * 7 * 64 * 8 * sizeof(__bf16));  // sincos(params/2)

  int B = in_sizes[0] / 784;
  wconv_kernel<<<dim3(25, 7), 64, 0, stream>>>(w_fc, var_params, wb, aux);
  fused_kernel<<<(B + G - 1) / G, 512, 0, stream>>>(
      x, wb, aux, w_lat, b_lat, b_fc, w_d1, b_d1, w_d2, b_d2, out, B);
}

// Round 10
// 127.385 us; speedup vs baseline: 1.1373x; 1.0083x over previous
//
#include <hip/hip_runtime.h>
#include <math.h>

#define G 16
#define HS 408          // hbuf sample stride (bf16), channel-last [s][pos*8+ci]; 816 B/sample,
                        // 16B-aligned so each phase-4 h-read is a single ds_read_b128
#define LSTR 232        // latb row stride (bf16): 464 B, 16B-aligned, 2-way-bank only
#define W1S 36          // wd1t pp-stride in floats: pp*36%32 = {0,4,8,12} distinct banks
                        // (pp*32 put all four pp rows in bank ci*4 -> 4-way conflict on every
                        // phase-4 weight read; measured 870k-3.3M SQ_LDS_BANK_CONFLICT)

typedef __attribute__((ext_vector_type(8))) __bf16 bf16x8;
typedef __attribute__((ext_vector_type(4))) float f32x4;
typedef __attribute__((ext_vector_type(2))) float f32x2;

// ---------------- Kernel W: swizzle w_fc (392x224 fp32) into bf16 MFMA B-fragments ----------
// wb[((tile*7 + kt)*64 + lane)*8 + j] = bf16(w_fc[n][k]), n = tile*16 + (lane&15),
// k = kt*32 + (lane>>4)*8 + j.  Tiles 0..24 (N padded 392->400 with zeros).
// Also writes aux[8] = {cos,sin}(0.5*params[q]) with the SAME __cosf/__sinf intrinsics ->
// bit-identical phase-1 results.
__global__ void wconv_kernel(const float* __restrict__ w_fc, const float* __restrict__ params,
                             __bf16* __restrict__ wb, float* __restrict__ aux) {
  int tile = blockIdx.x;      // 0..24
  int kt   = blockIdx.y;      // 0..6
  int lane = threadIdx.x;     // 0..63
  int n  = tile * 16 + (lane & 15);
  int k0 = kt * 32 + (lane >> 4) * 8;
  bf16x8 v;
  if (n < 392) {
    const float* src = w_fc + (size_t)n * 224 + k0;
    float4 f0 = *(const float4*)(src);
    float4 f1 = *(const float4*)(src + 4);
    v[0] = (__bf16)f0.x; v[1] = (__bf16)f0.y; v[2] = (__bf16)f0.z; v[3] = (__bf16)f0.w;
    v[4] = (__bf16)f1.x; v[5] = (__bf16)f1.y; v[6] = (__bf16)f1.z; v[7] = (__bf16)f1.w;
  } else {
    #pragma unroll
    for (int j = 0; j < 8; ++j) v[j] = (__bf16)0.f;
  }
  *(bf16x8*)(wb + ((size_t)(tile * 7 + kt) * 64 + lane) * 8) = v;
  if (tile == 0 && kt == 0 && lane < 4) {
    float hp = 0.5f * params[lane];
    aux[2 * lane]     = __cosf(hp);
    aux[2 * lane + 1] = __sinf(hp);
  }
}

// ---------------- Fused kernel: one block = 16 samples, 512 threads = 8 waves ----------------
// PROVEN STRUCTURE (r9, 128.44 us total): grid 1024 x 8 waves = 32 waves/CU full residency,
// plain L3-hot x loads, incremental phase-4 indexing, rcpf sigmoid, horizontal-add phase 0.
// This round: single change — wd1t pp-stride 32 -> 36 floats (W1S) to debank the phase-4
// broadcast weight reads (4-way same-bank -> conflict-free). Same values read, same fmaf
// chains -> bit-identical output.
// HARD CONSTRAINTS: VGPR <= 64 under launch_bounds(512,8) (r4 spill lesson), regular
// row-contiguous f32x2 stores (r1 lesson), no structural departures (r1/r3/r7 lessons).
__global__ __launch_bounds__(512, 8) void fused_kernel(
    const float* __restrict__ x,
    const __bf16* __restrict__ wb, const float* __restrict__ aux,
    const float* __restrict__ w_lat, const float* __restrict__ b_lat,
    const float* __restrict__ b_fc,
    const float* __restrict__ w_d1, const float* __restrict__ b_d1,
    const float* __restrict__ w_d2, const float* __restrict__ b_d2,
    float* __restrict__ out, int B)
{
  __shared__ __align__(16) __bf16 latb[G * LSTR];   // 7424 B
  __shared__ __align__(16) __bf16 hbuf[G * HS];     // 13056 B, channel-last: [s][pos49][ci8]
  __shared__ __align__(16) float qfs[G * 4];        // means, then <Z_q>; wave-private regions
  __shared__ __align__(16) float wd1t[4 * W1S];     // wd1t[pp*W1S + ci*4 + co] = w_d1[ci*16+co*4+pp]
  __shared__ __align__(16) float wd2[16];
  __shared__ __align__(16) float bd1[4];
  const int t = threadIdx.x;
  const int wv = t >> 6;         // 0..7
  const int lane = t & 63;
  const int s0g = blockIdx.x * G;
  if (s0g >= B) return;

  if (t < 128) {
    int ci = t >> 4, co = (t >> 2) & 3, p = t & 3;
    wd1t[p * W1S + ci * 4 + co] = w_d1[t];
  }
  else if (t < 144) wd2[t - 128] = w_d2[t - 128];
  else if (t < 148) bd1[t - 144] = b_d1[t - 144];

  // ---- Phase 0 (wave-local): quadrant sums for samples wv*2, wv*2+1. PLAIN loads (L3-hot).
  // Horizontal-add restructure: float4 at cb in {0,4,8} all-left, {16,20,24} all-right,
  // cb==12 splits (cols 12,13 | 14,15). tp/bt are exact 0/1 factors.
  {
    const float* xb = x + (size_t)(s0g + wv * 2) * 784;
    f32x4 vb[2][4];
    #pragma unroll
    for (int smp = 0; smp < 2; ++smp)
      #pragma unroll
      for (int it = 0; it < 4; ++it) {
        int i4 = lane + it * 64;
        if (i4 < 196)
          vb[smp][it] = *(const f32x4*)(xb + smp * 784 + i4 * 4);
        else
          vb[smp][it] = (f32x4){0.f, 0.f, 0.f, 0.f};
      }
    float acc[2][4];   // [smp][quad: TL,TR,BL,BR]
    #pragma unroll
    for (int i = 0; i < 2; ++i)
      #pragma unroll
      for (int q = 0; q < 4; ++q) acc[i][q] = 0.f;
    #pragma unroll
    for (int it = 0; it < 4; ++it) {
      int i4 = lane + it * 64;
      int base = i4 * 4;
      int r = base / 28;
      int cb = base - r * 28;          // float4 never crosses a row (28 % 4 == 0)
      float bt = (r >= 14) ? 1.f : 0.f;
      float tp = 1.f - bt;             // i4 >= 196 lanes loaded zeros, contribute nothing
      bool leftall = (cb < 12);
      bool split   = (cb == 12);
      #pragma unroll
      for (int smp = 0; smp < 2; ++smp) {
        f32x4 v = vb[smp][it];
        float ls = v[0] + v[1];
        float rs = v[2] + v[3];
        float al = ls + rs;
        float lsum = leftall ? al : (split ? ls : 0.f);
        float rsum = leftall ? 0.f : (split ? rs : al);
        acc[smp][0] = fmaf(lsum, tp, acc[smp][0]);
        acc[smp][1] = fmaf(rsum, tp, acc[smp][1]);
        acc[smp][2] = fmaf(lsum, bt, acc[smp][2]);
        acc[smp][3] = fmaf(rsum, bt, acc[smp][3]);
      }
    }
    #pragma unroll
    for (int smp = 0; smp < 2; ++smp)
      #pragma unroll
      for (int q = 0; q < 4; ++q)
        #pragma unroll
        for (int o = 32; o > 0; o >>= 1)
          acc[smp][q] += __shfl_down(acc[smp][q], o, 64);
    if (lane == 0) {
      const float inv = 1.f / 196.f;
      #pragma unroll
      for (int smp = 0; smp < 2; ++smp) {
        float4 o;
        o.x = acc[smp][0] * inv; o.y = acc[smp][1] * inv;
        o.z = acc[smp][2] * inv; o.w = acc[smp][3] * inv;
        *(float4*)(qfs + (wv * 2 + smp) * 4) = o;
      }
    }
  }
  // no barrier: phases 0-2 stay within the wave (DS ops are in-order per wave)

  // ---- Phase 1 (wave-local, lane-parallel, ALL 64 lanes): 16 lanes per sample;
  // lane-groups 2,3 duplicate groups 0,1 so shuffles run with full exec mask.
  {
    const int sub = lane >> 4;          // 0..3
    const int i   = lane & 15;          // amplitude index; qubit q <-> bit (3-q)
    const int s   = wv * 2 + (sub & 1); // groups 0/2 -> sample 0, 1/3 -> sample 1
    float4 mn = *(const float4*)(qfs + s * 4);
    float c_[4], s_[4];
    c_[0] = __cosf(0.5f * mn.x); s_[0] = __sinf(0.5f * mn.x);
    c_[1] = __cosf(0.5f * mn.y); s_[1] = __sinf(0.5f * mn.y);
    c_[2] = __cosf(0.5f * mn.z); s_[2] = __sinf(0.5f * mn.z);
    c_[3] = __cosf(0.5f * mn.w); s_[3] = __sinf(0.5f * mn.w);
    float re = (((i >> 3) & 1) ? s_[0] : c_[0]) * (((i >> 2) & 1) ? s_[1] : c_[1])
             * (((i >> 1) & 1) ? s_[2] : c_[2]) * ((i & 1) ? s_[3] : c_[3]);
    float im = 0.f;
    #pragma unroll
    for (int q = 0; q < 4; ++q) {
      float cp = aux[2 * q], sp = aux[2 * q + 1];   // precomputed in wconv, bit-identical
      int qb = 3 - q;
      float sg = ((i >> qb) & 1) ? sp : -sp;     // exp(+-i p/2)
      float r0 = re, i0 = im;
      re = r0 * cp - i0 * sg;
      im = r0 * sg + i0 * cp;
      int cm = 1 << qb;
      int tm = 1 << (3 - ((q + 1) & 3));
      int srcI = (i & cm) ? (i ^ tm) : i;        // CNOT: new[i] = old[i^tm] if control set
      int srcLane = (lane & ~15) | srcI;
      re = __shfl(re, srcLane, 64);
      im = __shfl(im, srcLane, 64);
    }
    float p = re * re + im * im;
    float z[4];
    #pragma unroll
    for (int q = 0; q < 4; ++q) {
      int qb = 3 - q;
      float v = ((i >> qb) & 1) ? -p : p;
      v += __shfl_xor(v, 1, 16);
      v += __shfl_xor(v, 2, 16);
      v += __shfl_xor(v, 4, 16);
      v += __shfl_xor(v, 8, 16);
      z[q] = v;
    }
    if (sub < 2 && i < 4) {             // guard only the write; shuffles are done
      float zv = (i == 0) ? z[0] : (i == 1) ? z[1] : (i == 2) ? z[2] : z[3];
      qfs[s * 4 + i] = zv;
    }
  }

  // ---- Phase 2 (wave-local): latent[s][j] = relu(qf[s] . w_lat[j] + b_lat[j]) -> bf16 LDS
  #pragma unroll
  for (int sl = 0; sl < 2; ++sl) {
    int s = wv * 2 + sl;
    float4 q4 = *(const float4*)(qfs + s * 4);
    for (int j = lane; j < 224; j += 64) {
      float4 w = *(const float4*)(w_lat + j * 4);
      float a = b_lat[j];
      a = fmaf(q4.x, w.x, a);
      a = fmaf(q4.y, w.y, a);
      a = fmaf(q4.z, w.z, a);
      a = fmaf(q4.w, w.w, a);
      latb[s * LSTR + j] = (__bf16)fmaxf(a, 0.f);
    }
  }
  __syncthreads();

  // ---- Phase 3: MFMA. wave wv handles N-tiles wv, wv+8, wv+16, (wv+24).
  // D written channel-last: j -> (ci = j/49, pos = j%49), hbuf[s][pos*8 + ci].
  {
    const int m = lane & 15;       // A-row (sample) AND B/D-col (n) index
    const int kq = lane >> 4;      // k-quad
    const __bf16* arow = latb + m * LSTR + kq * 8;
    for (int tile = wv; tile < 25; tile += 8) {
      f32x4 acc = {0.f, 0.f, 0.f, 0.f};
      const bf16x8* bp = (const bf16x8*)(wb + ((size_t)(tile * 7) * 64 + lane) * 8);
      #pragma unroll
      for (int kt = 0; kt < 7; ++kt) {
        bf16x8 a = *(const bf16x8*)(arow + kt * 32);
        bf16x8 b = bp[kt * 64];
        acc = __builtin_amdgcn_mfma_f32_16x16x32_bf16(a, b, acc, 0, 0, 0);
      }
      int j = tile * 16 + m;
      if (j < 392) {
        float bf = b_fc[j];
        int ci = j / 49;
        int off = (j - ci * 49) * 8 + ci;
        #pragma unroll
        for (int r = 0; r < 4; ++r)
          hbuf[(kq * 4 + r) * HS + off] = (__bf16)fmaxf(acc[r] + bf, 0.f);
      }
    }
  }
  __syncthreads();

  // ---- Phase 4: one thread = one 2x2 output quarter; h via ONE ds_read_b128, wd1 via
  // debanked broadcast b128 reads of wd1t (W1S stride), wd2/b1 in regs, incremental (s,Y,X)
  // indexing, rcpf sigmoid. All r9-proven; only the wd1t bank layout changed this round.
  {
    f32x4 w2v[4];
    #pragma unroll
    for (int co = 0; co < 4; ++co) w2v[co] = *(const f32x4*)(wd2 + co * 4);
    f32x4 b1v = *(const f32x4*)(bd1);
    const float bd2v = b_d2[0];
    int s, Y, X;
    {
      int v0 = t;
      s = v0 / 196;
      int p = v0 - s * 196;
      Y = p / 14;
      X = p - Y * 14;
    }
    for (int v = t; v < G * 196; v += 512) {
      int y = Y >> 1, ey = Y & 1, xx = X >> 1, ex = X & 1;
      int pp = ey * 2 + ex;
      bf16x8 hb = *(const bf16x8*)(hbuf + s * HS + (y * 7 + xx) * 8);
      float o1[4];
      #pragma unroll
      for (int co = 0; co < 4; ++co) o1[co] = b1v[co];
      #pragma unroll
      for (int ci = 0; ci < 8; ++ci) {
        f32x4 w4 = *(const f32x4*)(wd1t + pp * W1S + ci * 4);  // 4 addrs/wave, distinct banks
        float h = (float)hb[ci];
        #pragma unroll
        for (int co = 0; co < 4; ++co) o1[co] = fmaf(h, w4[co], o1[co]);
      }
      #pragma unroll
      for (int co = 0; co < 4; ++co) o1[co] = fmaxf(o1[co], 0.f);
      size_t basep = (size_t)(s0g + s) * 784;
      #pragma unroll
      for (int dy = 0; dy < 2; ++dy) {
        float v0 = bd2v, v1 = bd2v;
        #pragma unroll
        for (int co = 0; co < 4; ++co) {
          v0 = fmaf(o1[co], w2v[co][dy * 2 + 0], v0);
          v1 = fmaf(o1[co], w2v[co][dy * 2 + 1], v1);
        }
        f32x2 o;
        o[0] = __builtin_amdgcn_rcpf(1.f + __expf(-v0));
        o[1] = __builtin_amdgcn_rcpf(1.f + __expf(-v1));
        *(f32x2*)(out + basep + (size_t)(2 * Y + dy) * 28 + 2 * X) = o;
      }
      // advance to v + 512: maintain v = s*196 + Y*14 + X, 0<=X<14, 0<=Y<14
      s += 2; Y += 8; X += 8;
      if (X >= 14) { X -= 14; Y += 1; }
      if (Y >= 14) { Y -= 14; s += 1; }
    }
  }
}

extern "C" void kernel_launch(void* const* d_in, const int* in_sizes, int n_in,
                              void* d_out, int out_size, void* d_ws, size_t ws_size,
                              hipStream_t stream) {
  const float* x          = (const float*)d_in[0];
  const float* var_params = (const float*)d_in[1];
  const float* w_lat      = (const float*)d_in[2];
  const float* b_lat      = (const float*)d_in[3];
  const float* w_fc       = (const float*)d_in[4];
  const float* b_fc       = (const float*)d_in[5];
  const float* w_d1       = (const float*)d_in[6];
  const float* b_d1       = (const float*)d_in[7];
  const float* w_d2       = (const float*)d_in[8];
  const float* b_d2       = (const float*)d_in[9];
  float* out = (float*)d_out;

  __bf16* wb = (__bf16*)d_ws;   // 25*7*64*8 bf16 = 179200 B of swizzled w_fc fragments
  float* aux = (float*)((char*)d_ws + (size_t)25 * 7 * 64 * 8 * sizeof(__bf16));  // sincos(params/2)

  int B = in_sizes[0] / 784;
  wconv_kernel<<<dim3(25, 7), 64, 0, stream>>>(w_fc, var_params, wb, aux);
  fused_kernel<<<(B + G - 1) / G, 512, 0, stream>>>(
      x, wb, aux, w_lat, b_lat, b_fc, w_d1, b_d1, w_d2, b_d2, out, B);
}